// Round 1
// baseline (731.200 us; speedup 1.0000x reference)
//
#include <hip/hip_runtime.h>
#include <hip/hip_bf16.h>

#define NTOK 4096   // 64*64 tokens per batch
#define NPOOL 1024  // 32*32 pooled tokens per batch

// Map local tile row m (0..63) to a global x row such that rows 4*p..4*p+3 are
// the 2x2 pooling corners of pooled row blockIdx.x*16+p.
__device__ __forceinline__ int pool_row(int bx, int m) {
  int pg = bx * 16 + (m >> 2);   // global pooled row (0..8191)
  int corner = m & 3;
  int batch = pg >> 10;
  int pl = pg & 1023;
  int pi = pl >> 5, pj = pl & 31;
  return (batch << 12) + ((2 * pi + (corner >> 1)) << 6) + 2 * pj + (corner & 1);
}

// C = A[M,K] @ W[K,N]; optional fused 2x2 maxpool (rows grouped by pool_row),
// optional fused residual epilogue out = gamma*acc + Xres.
template <bool POOL, bool RESID>
__global__ __launch_bounds__(256) void gemm_k(const float* __restrict__ A,
                                              const float* __restrict__ W,
                                              float* __restrict__ Out,
                                              const float* __restrict__ Xres,
                                              const float* __restrict__ gamma,
                                              int K, int N) {
  __shared__ float As[32][68];  // [k][m], +4 pad keeps float4 alignment
  __shared__ float Bs[32][68];  // [k][n]
  const int tid = threadIdx.x;
  const int tx = tid & 15, ty = tid >> 4;
  float acc[4][4] = {};
  const int kTiles = K >> 5;
  for (int kt = 0; kt < kTiles; ++kt) {
#pragma unroll
    for (int r = 0; r < 2; ++r) {
      int j = tid + r * 256;                 // 512 float4 = 64 rows x 32 k
      int m = j >> 3, k4 = (j & 7) << 2;
      int row = POOL ? pool_row(blockIdx.x, m) : ((int)blockIdx.x * 64 + m);
      float4 v = *(const float4*)(A + (size_t)row * K + kt * 32 + k4);
      As[k4 + 0][m] = v.x; As[k4 + 1][m] = v.y;
      As[k4 + 2][m] = v.z; As[k4 + 3][m] = v.w;
    }
#pragma unroll
    for (int r = 0; r < 2; ++r) {
      int j = tid + r * 256;                 // 512 float4 = 32 k x 64 n
      int k = j >> 4, c4 = (j & 15) << 2;
      *(float4*)&Bs[k][c4] =
          *(const float4*)(W + (size_t)(kt * 32 + k) * N + (size_t)blockIdx.y * 64 + c4);
    }
    __syncthreads();
#pragma unroll
    for (int k = 0; k < 32; ++k) {
      float4 a = *(const float4*)&As[k][ty << 2];
      float4 b = *(const float4*)&Bs[k][tx << 2];
      float av[4] = {a.x, a.y, a.z, a.w};
      float bv[4] = {b.x, b.y, b.z, b.w};
#pragma unroll
      for (int i = 0; i < 4; ++i)
#pragma unroll
        for (int jj = 0; jj < 4; ++jj) acc[i][jj] += av[i] * bv[jj];
    }
    __syncthreads();
  }
  const int cb = (int)blockIdx.y * 64 + (tx << 2);
  if (POOL) {
    int pr = (int)blockIdx.x * 16 + ty;      // pooled output row
    float4 v;
    v.x = fmaxf(fmaxf(acc[0][0], acc[1][0]), fmaxf(acc[2][0], acc[3][0]));
    v.y = fmaxf(fmaxf(acc[0][1], acc[1][1]), fmaxf(acc[2][1], acc[3][1]));
    v.z = fmaxf(fmaxf(acc[0][2], acc[1][2]), fmaxf(acc[2][2], acc[3][2]));
    v.w = fmaxf(fmaxf(acc[0][3], acc[1][3]), fmaxf(acc[2][3], acc[3][3]));
    *(float4*)(Out + (size_t)pr * N + cb) = v;
  } else {
    float gm = RESID ? gamma[0] : 0.0f;
#pragma unroll
    for (int i = 0; i < 4; ++i) {
      int r = (int)blockIdx.x * 64 + (ty << 2) + i;
      float4 v = make_float4(acc[i][0], acc[i][1], acc[i][2], acc[i][3]);
      if (RESID) {
        float4 xr = *(const float4*)(Xres + (size_t)r * 512 + cb);
        v.x = gm * v.x + xr.x; v.y = gm * v.y + xr.y;
        v.z = gm * v.z + xr.z; v.w = gm * v.w + xr.w;
      }
      *(float4*)(Out + (size_t)r * N + cb) = v;
    }
  }
}

// Flash-style attention: one block per (batch, 64-query tile). K-chunk = 32.
// o[b,q,:] = softmax_k(g[b,q,:].f[b,k,:]) @ h[b,k,:]
__global__ __launch_bounds__(256) void attn_k(const float* __restrict__ G,
                                              const float* __restrict__ F,
                                              const float* __restrict__ Hm,
                                              float* __restrict__ O) {
  __shared__ __hip_bfloat16 gS[64][64];  // [d][q] (bf16 to fit 64KB LDS)
  __shared__ float fS[64][32];           // [d][k]
  __shared__ float sS[64][36];           // [q][k] scores then probs; pad 36
  __shared__ float hS[32][256];          // [k][dv]
  __shared__ float mS[64], lS[64], aS[64];

  const int tid = threadIdx.x;
  const int b = blockIdx.x >> 6, qt = blockIdx.x & 63;
  const float* Gb = G + ((size_t)b * NTOK + qt * 64) * 64;
  const float* Fb = F + (size_t)b * NPOOL * 64;
  const float* Hb = Hm + (size_t)b * NPOOL * 256;

#pragma unroll
  for (int r = 0; r < 4; ++r) {            // stage g tile, transposed, bf16
    int j = tid + r * 256;                 // 1024 float4
    int q = j >> 4, d4 = (j & 15) << 2;
    float4 v = *(const float4*)(Gb + q * 64 + d4);
    gS[d4 + 0][q] = __float2bfloat16(v.x);
    gS[d4 + 1][q] = __float2bfloat16(v.y);
    gS[d4 + 2][q] = __float2bfloat16(v.z);
    gS[d4 + 3][q] = __float2bfloat16(v.w);
  }
  if (tid < 64) { mS[tid] = -1e30f; lS[tid] = 0.0f; }

  const int qg = tid >> 4, dg = tid & 15;  // thread owns q=4*qg+i, d=64u+4*dg+e
  float4 acc[4][4];
#pragma unroll
  for (int i = 0; i < 4; ++i)
#pragma unroll
    for (int u = 0; u < 4; ++u) acc[i][u] = make_float4(0.f, 0.f, 0.f, 0.f);

  for (int kc = 0; kc < 32; ++kc) {
    __syncthreads();  // prev PV done (also covers g-staging before kc=0)
#pragma unroll
    for (int r = 0; r < 2; ++r) {          // stage f chunk, transposed
      int j = tid + r * 256;               // 512 float4
      int k = j >> 4, d4 = (j & 15) << 2;
      float4 v = *(const float4*)(Fb + (size_t)(kc * 32 + k) * 64 + d4);
      fS[d4 + 0][k] = v.x; fS[d4 + 1][k] = v.y;
      fS[d4 + 2][k] = v.z; fS[d4 + 3][k] = v.w;
    }
#pragma unroll
    for (int r = 0; r < 8; ++r) {          // stage h chunk
      int j = tid + r * 256;               // 2048 float4
      int k = j >> 6, c4 = (j & 63) << 2;
      *(float4*)&hS[k][c4] = *(const float4*)(Hb + (size_t)(kc * 32 + k) * 256 + c4);
    }
    __syncthreads();
    {  // scores: thread computes 2q x 4k
      const int qb = (tid >> 3) << 1;
      const int kb = (tid & 7) << 2;
      float c0[4] = {}, c1[4] = {};
#pragma unroll
      for (int d = 0; d < 64; ++d) {
        float g0 = __bfloat162float(gS[d][qb]);
        float g1 = __bfloat162float(gS[d][qb + 1]);
        float4 fv = *(const float4*)&fS[d][kb];
        c0[0] += g0 * fv.x; c0[1] += g0 * fv.y; c0[2] += g0 * fv.z; c0[3] += g0 * fv.w;
        c1[0] += g1 * fv.x; c1[1] += g1 * fv.y; c1[2] += g1 * fv.z; c1[3] += g1 * fv.w;
      }
      *(float4*)&sS[qb][kb] = make_float4(c0[0], c0[1], c0[2], c0[3]);
      *(float4*)&sS[qb + 1][kb] = make_float4(c1[0], c1[1], c1[2], c1[3]);
    }
    __syncthreads();
    {  // online softmax: 4 consecutive lanes per row (same wave -> lockstep)
      const int q = tid >> 2, part = tid & 3;
      const int kb = part * 8;
      float4 v0 = *(const float4*)&sS[q][kb];
      float4 v1 = *(const float4*)&sS[q][kb + 4];
      float cm = fmaxf(fmaxf(fmaxf(v0.x, v0.y), fmaxf(v0.z, v0.w)),
                       fmaxf(fmaxf(v1.x, v1.y), fmaxf(v1.z, v1.w)));
      cm = fmaxf(cm, __shfl_xor(cm, 1));
      cm = fmaxf(cm, __shfl_xor(cm, 2));
      float mo = mS[q];
      float mn = fmaxf(mo, cm);
      v0.x = __expf(v0.x - mn); v0.y = __expf(v0.y - mn);
      v0.z = __expf(v0.z - mn); v0.w = __expf(v0.w - mn);
      v1.x = __expf(v1.x - mn); v1.y = __expf(v1.y - mn);
      v1.z = __expf(v1.z - mn); v1.w = __expf(v1.w - mn);
      float sum = v0.x + v0.y + v0.z + v0.w + v1.x + v1.y + v1.z + v1.w;
      *(float4*)&sS[q][kb] = v0;
      *(float4*)&sS[q][kb + 4] = v1;
      sum += __shfl_xor(sum, 1);
      sum += __shfl_xor(sum, 2);
      if (part == 0) {
        float al = __expf(mo - mn);
        aS[q] = al;
        mS[q] = mn;
        lS[q] = al * lS[q] + sum;
      }
    }
    __syncthreads();
    {  // PV accumulate
      float al[4];
#pragma unroll
      for (int i = 0; i < 4; ++i) al[i] = aS[qg * 4 + i];
#pragma unroll
      for (int i = 0; i < 4; ++i)
#pragma unroll
        for (int u = 0; u < 4; ++u) {
          acc[i][u].x *= al[i]; acc[i][u].y *= al[i];
          acc[i][u].z *= al[i]; acc[i][u].w *= al[i];
        }
#pragma unroll 4
      for (int k = 0; k < 32; ++k) {
        float p0 = sS[qg * 4 + 0][k], p1 = sS[qg * 4 + 1][k];
        float p2 = sS[qg * 4 + 2][k], p3 = sS[qg * 4 + 3][k];
#pragma unroll
        for (int u = 0; u < 4; ++u) {
          float4 hv = *(const float4*)&hS[k][u * 64 + (dg << 2)];
          acc[0][u].x += p0 * hv.x; acc[0][u].y += p0 * hv.y;
          acc[0][u].z += p0 * hv.z; acc[0][u].w += p0 * hv.w;
          acc[1][u].x += p1 * hv.x; acc[1][u].y += p1 * hv.y;
          acc[1][u].z += p1 * hv.z; acc[1][u].w += p1 * hv.w;
          acc[2][u].x += p2 * hv.x; acc[2][u].y += p2 * hv.y;
          acc[2][u].z += p2 * hv.z; acc[2][u].w += p2 * hv.w;
          acc[3][u].x += p3 * hv.x; acc[3][u].y += p3 * hv.y;
          acc[3][u].z += p3 * hv.z; acc[3][u].w += p3 * hv.w;
        }
      }
    }
  }
  float inv[4];
#pragma unroll
  for (int i = 0; i < 4; ++i) inv[i] = 1.0f / lS[qg * 4 + i];
#pragma unroll
  for (int i = 0; i < 4; ++i) {
    size_t row = (size_t)b * NTOK + qt * 64 + qg * 4 + i;
#pragma unroll
    for (int u = 0; u < 4; ++u) {
      float4 v = acc[i][u];
      v.x *= inv[i]; v.y *= inv[i]; v.z *= inv[i]; v.w *= inv[i];
      *(float4*)(O + row * 256 + u * 64 + (dg << 2)) = v;
    }
  }
}

extern "C" void kernel_launch(void* const* d_in, const int* in_sizes, int n_in,
                              void* d_out, int out_size, void* d_ws, size_t ws_size,
                              hipStream_t stream) {
  (void)in_sizes; (void)n_in; (void)out_size; (void)ws_size;
  const float* x     = (const float*)d_in[0];  // [8,64,64,512]
  const float* wf    = (const float*)d_in[1];  // [512,64]
  const float* wg    = (const float*)d_in[2];  // [512,64]
  const float* wh    = (const float*)d_in[3];  // [512,256]
  const float* wo    = (const float*)d_in[4];  // [256,512]
  const float* gamma = (const float*)d_in[5];  // [1]
  float* out = (float*)d_out;

  float* ws = (float*)d_ws;
  float* gB = ws;                    // [8*4096, 64]  = 2,097,152 f
  float* fB = gB + 2097152;          // [8*1024, 64]  =   524,288 f
  float* hB = fB + 524288;           // [8*1024, 256] = 2,097,152 f
  float* oB = hB + 2097152;          // [8*4096, 256] = 8,388,608 f  (total 50 MB)

  dim3 blk(256);
  // g = x @ wg                         rows 32768/64 = 512 tiles
  gemm_k<false, false><<<dim3(512, 1), blk, 0, stream>>>(x, wg, gB, nullptr, nullptr, 512, 64);
  // f = maxpool(x @ wf)                pooled rows 8192/16 = 512 tiles
  gemm_k<true, false><<<dim3(512, 1), blk, 0, stream>>>(x, wf, fB, nullptr, nullptr, 512, 64);
  // h = maxpool(x @ wh)
  gemm_k<true, false><<<dim3(512, 4), blk, 0, stream>>>(x, wh, hB, nullptr, nullptr, 512, 256);
  // o = softmax(g f^T) h               8 batches x 64 query tiles
  attn_k<<<512, 256, 0, stream>>>(gB, fB, hB, oB);
  // out = gamma * (o @ wo) + x
  gemm_k<false, true><<<dim3(512, 8), blk, 0, stream>>>(oB, wo, out, x, gamma, 256, 512);
}

// Round 3
// 475.992 us; speedup vs baseline: 1.5362x; 1.5362x over previous
//
#include <hip/hip_runtime.h>
#include <hip/hip_bf16.h>

#define NTOK 4096   // 64*64 tokens per batch
#define NPOOL 1024  // 32*32 pooled tokens per batch

using short8 = __attribute__((ext_vector_type(8))) short;
using f32x4  = __attribute__((ext_vector_type(4))) float;

__device__ __forceinline__ unsigned short f2bf(float f) {
  __hip_bfloat16 h = __float2bfloat16(f);
  return __builtin_bit_cast(unsigned short, h);
}

// Map local tile row m (0..63) to a global x row such that rows 4*p..4*p+3 are
// the 2x2 pooling corners of pooled row blockIdx.x*16+p.
__device__ __forceinline__ int pool_row(int bx, int m) {
  int pg = bx * 16 + (m >> 2);   // global pooled row (0..8191)
  int corner = m & 3;
  int batch = pg >> 10;
  int pl = pg & 1023;
  int pi = pl >> 5, pj = pl & 31;
  return (batch << 12) + ((2 * pi + (corner >> 1)) << 6) + 2 * pj + (corner & 1);
}

// fp32-compute GEMM, bf16 output. POOL: fused 2x2 maxpool on rows.
// Used for g (POOL=false, N=64) and f (POOL=true, N=64).
template <bool POOL>
__global__ __launch_bounds__(256) void gemm_fg(const float* __restrict__ A,
                                               const float* __restrict__ W,
                                               __hip_bfloat16* __restrict__ Out,
                                               int K, int N) {
  __shared__ float As[32][68];
  __shared__ float Bs[32][68];
  const int tid = threadIdx.x;
  const int tx = tid & 15, ty = tid >> 4;
  float acc[4][4] = {};
  const int kTiles = K >> 5;
  for (int kt = 0; kt < kTiles; ++kt) {
#pragma unroll
    for (int r = 0; r < 2; ++r) {
      int j = tid + r * 256;
      int m = j >> 3, k4 = (j & 7) << 2;
      int row = POOL ? pool_row(blockIdx.x, m) : ((int)blockIdx.x * 64 + m);
      float4 v = *(const float4*)(A + (size_t)row * K + kt * 32 + k4);
      As[k4 + 0][m] = v.x; As[k4 + 1][m] = v.y;
      As[k4 + 2][m] = v.z; As[k4 + 3][m] = v.w;
    }
#pragma unroll
    for (int r = 0; r < 2; ++r) {
      int j = tid + r * 256;
      int k = j >> 4, c4 = (j & 15) << 2;
      *(float4*)&Bs[k][c4] =
          *(const float4*)(W + (size_t)(kt * 32 + k) * N + (size_t)blockIdx.y * 64 + c4);
    }
    __syncthreads();
#pragma unroll
    for (int k = 0; k < 32; ++k) {
      float4 a = *(const float4*)&As[k][ty << 2];
      float4 b = *(const float4*)&Bs[k][tx << 2];
      float av[4] = {a.x, a.y, a.z, a.w};
      float bv[4] = {b.x, b.y, b.z, b.w};
#pragma unroll
      for (int i = 0; i < 4; ++i)
#pragma unroll
        for (int jj = 0; jj < 4; ++jj) acc[i][jj] += av[i] * bv[jj];
    }
    __syncthreads();
  }
  const int cb = (int)blockIdx.y * 64 + (tx << 2);
  if (POOL) {
    int pr = (int)blockIdx.x * 16 + ty;
    float v[4];
#pragma unroll
    for (int jj = 0; jj < 4; ++jj)
      v[jj] = fmaxf(fmaxf(acc[0][jj], acc[1][jj]), fmaxf(acc[2][jj], acc[3][jj]));
    ushort4 o;
    o.x = f2bf(v[0]); o.y = f2bf(v[1]);
    o.z = f2bf(v[2]); o.w = f2bf(v[3]);
    *(ushort4*)(Out + (size_t)pr * N + cb) = o;
  } else {
#pragma unroll
    for (int i = 0; i < 4; ++i) {
      int r = (int)blockIdx.x * 64 + (ty << 2) + i;
      ushort4 o;
      o.x = f2bf(acc[i][0]); o.y = f2bf(acc[i][1]);
      o.z = f2bf(acc[i][2]); o.w = f2bf(acc[i][3]);
      *(ushort4*)(Out + (size_t)r * N + cb) = o;
    }
  }
}

// fp32-compute pooled GEMM for h, writing TRANSPOSED bf16: hT[b][dv][1024 pooled].
__global__ __launch_bounds__(256) void gemm_hT(const float* __restrict__ A,
                                               const float* __restrict__ W,
                                               __hip_bfloat16* __restrict__ OutT,
                                               int K, int N) {
  __shared__ float As[32][68];
  __shared__ float Bs[32][68];
  __shared__ float tS[64][17];   // [dv_local][pr_local]
  const int tid = threadIdx.x;
  const int tx = tid & 15, ty = tid >> 4;
  float acc[4][4] = {};
  const int kTiles = K >> 5;
  for (int kt = 0; kt < kTiles; ++kt) {
#pragma unroll
    for (int r = 0; r < 2; ++r) {
      int j = tid + r * 256;
      int m = j >> 3, k4 = (j & 7) << 2;
      int row = pool_row(blockIdx.x, m);
      float4 v = *(const float4*)(A + (size_t)row * K + kt * 32 + k4);
      As[k4 + 0][m] = v.x; As[k4 + 1][m] = v.y;
      As[k4 + 2][m] = v.z; As[k4 + 3][m] = v.w;
    }
#pragma unroll
    for (int r = 0; r < 2; ++r) {
      int j = tid + r * 256;
      int k = j >> 4, c4 = (j & 15) << 2;
      *(float4*)&Bs[k][c4] =
          *(const float4*)(W + (size_t)(kt * 32 + k) * N + (size_t)blockIdx.y * 64 + c4);
    }
    __syncthreads();
#pragma unroll
    for (int k = 0; k < 32; ++k) {
      float4 a = *(const float4*)&As[k][ty << 2];
      float4 b = *(const float4*)&Bs[k][tx << 2];
      float av[4] = {a.x, a.y, a.z, a.w};
      float bv[4] = {b.x, b.y, b.z, b.w};
#pragma unroll
      for (int i = 0; i < 4; ++i)
#pragma unroll
        for (int jj = 0; jj < 4; ++jj) acc[i][jj] += av[i] * bv[jj];
    }
    __syncthreads();
  }
  // pooled result for pr_local=ty, dv_local = tx*4+e  -> stage transposed
#pragma unroll
  for (int e = 0; e < 4; ++e) {
    tS[tx * 4 + e][ty] =
        fmaxf(fmaxf(acc[0][e], acc[1][e]), fmaxf(acc[2][e], acc[3][e]));
  }
  __syncthreads();
  // coalesced transposed write: thread t -> dv_local = t>>2, 4 pr starting (t&3)*4
  const int dvl = tid >> 2, pg = (tid & 3) << 2;
  const int b = blockIdx.x >> 6;                 // 64 blocks per batch
  const int pkb = ((int)blockIdx.x & 63) * 16;   // pooled index base within batch
  const int dvg = (int)blockIdx.y * 64 + dvl;
  ushort4 o;
  o.x = f2bf(tS[dvl][pg + 0]);
  o.y = f2bf(tS[dvl][pg + 1]);
  o.z = f2bf(tS[dvl][pg + 2]);
  o.w = f2bf(tS[dvl][pg + 3]);
  *(ushort4*)(OutT + ((size_t)b * 256 + dvg) * NPOOL + pkb + pg) = o;
}

// fp32 GEMM with fused residual: out = gamma*(A@W) + Xres. A=[32768,256], W=[256,512].
__global__ __launch_bounds__(256) void gemm_out(const float* __restrict__ A,
                                                const float* __restrict__ W,
                                                float* __restrict__ Out,
                                                const float* __restrict__ Xres,
                                                const float* __restrict__ gamma,
                                                int K, int N) {
  __shared__ float As[32][68];
  __shared__ float Bs[32][68];
  const int tid = threadIdx.x;
  const int tx = tid & 15, ty = tid >> 4;
  float acc[4][4] = {};
  const int kTiles = K >> 5;
  for (int kt = 0; kt < kTiles; ++kt) {
#pragma unroll
    for (int r = 0; r < 2; ++r) {
      int j = tid + r * 256;
      int m = j >> 3, k4 = (j & 7) << 2;
      int row = (int)blockIdx.x * 64 + m;
      float4 v = *(const float4*)(A + (size_t)row * K + kt * 32 + k4);
      As[k4 + 0][m] = v.x; As[k4 + 1][m] = v.y;
      As[k4 + 2][m] = v.z; As[k4 + 3][m] = v.w;
    }
#pragma unroll
    for (int r = 0; r < 2; ++r) {
      int j = tid + r * 256;
      int k = j >> 4, c4 = (j & 15) << 2;
      *(float4*)&Bs[k][c4] =
          *(const float4*)(W + (size_t)(kt * 32 + k) * N + (size_t)blockIdx.y * 64 + c4);
    }
    __syncthreads();
#pragma unroll
    for (int k = 0; k < 32; ++k) {
      float4 a = *(const float4*)&As[k][ty << 2];
      float4 b = *(const float4*)&Bs[k][tx << 2];
      float av[4] = {a.x, a.y, a.z, a.w};
      float bv[4] = {b.x, b.y, b.z, b.w};
#pragma unroll
      for (int i = 0; i < 4; ++i)
#pragma unroll
        for (int jj = 0; jj < 4; ++jj) acc[i][jj] += av[i] * bv[jj];
    }
    __syncthreads();
  }
  const int cb = (int)blockIdx.y * 64 + (tx << 2);
  float gm = gamma[0];
#pragma unroll
  for (int i = 0; i < 4; ++i) {
    int r = (int)blockIdx.x * 64 + (ty << 2) + i;
    float4 xr = *(const float4*)(Xres + (size_t)r * 512 + cb);
    float4 v;
    v.x = gm * acc[i][0] + xr.x; v.y = gm * acc[i][1] + xr.y;
    v.z = gm * acc[i][2] + xr.z; v.w = gm * acc[i][3] + xr.w;
    *(float4*)(Out + (size_t)r * N + cb) = v;
  }
}

// MFMA flash attention. Block = 64 queries (4 waves x 16q), K-chunk = 64 keys.
// G: bf16 [b][4096][64]  (A operand, natural)
// F: bf16 [b][1024][64]  (B operand for QK^T, natural)
// HT: bf16 [b][256][1024] (B operand for PV, key-contiguous)
__global__ __launch_bounds__(256) void attn_mfma(const __hip_bfloat16* __restrict__ G,
                                                 const __hip_bfloat16* __restrict__ F,
                                                 const __hip_bfloat16* __restrict__ HT,
                                                 float* __restrict__ O) {
  __shared__ __hip_bfloat16 gS[64][72];   // [q][d]
  __shared__ __hip_bfloat16 fS[64][72];   // [k][d]
  __shared__ __hip_bfloat16 hS[256][72];  // [dv][k]
  __shared__ __hip_bfloat16 pS[64][72];   // [q][k]

  const int tid = threadIdx.x;
  const int wave = tid >> 6, lane = tid & 63;
  const int col = lane & 15;     // A-row / B-col within a 16-tile
  const int rgrp = lane >> 4;    // k-group for fragments; row-group for C
  const int b = blockIdx.x >> 6, qt = blockIdx.x & 63;

  const __hip_bfloat16* Gb = G + ((size_t)b * NTOK + qt * 64) * 64;
  const __hip_bfloat16* Fb = F + (size_t)b * NPOOL * 64;
  const __hip_bfloat16* Hb = HT + (size_t)b * 256 * NPOOL;

  // stage g tile [64][64]
#pragma unroll
  for (int r = 0; r < 2; ++r) {
    int j = tid + r * 256;
    int q = j >> 3, d8 = (j & 7) << 3;
    *(uint4*)&gS[q][d8] = *(const uint4*)(Gb + (size_t)q * 64 + d8);
  }
  __syncthreads();

  // g A-fragments (chunk-invariant): row = col (q), k = rgrp*8.. (+32 per kstep)
  short8 ag[2];
#pragma unroll
  for (int ks = 0; ks < 2; ++ks)
    ag[ks] = *(const short8*)&gS[wave * 16 + col][ks * 32 + rgrp * 8];

  f32x4 oacc[16];
#pragma unroll
  for (int t = 0; t < 16; ++t) oacc[t] = (f32x4){0.f, 0.f, 0.f, 0.f};
  float m_run[4], l_run[4];
#pragma unroll
  for (int r = 0; r < 4; ++r) { m_run[r] = -1e30f; l_run[r] = 0.f; }

  for (int kc = 0; kc < 16; ++kc) {
    __syncthreads();  // all waves done reading fS/hS from prev chunk
    // stage f chunk [64 keys][64 d]
#pragma unroll
    for (int r = 0; r < 2; ++r) {
      int j = tid + r * 256;
      int k = j >> 3, d8 = (j & 7) << 3;
      *(uint4*)&fS[k][d8] = *(const uint4*)(Fb + (size_t)(kc * 64 + k) * 64 + d8);
    }
    // stage h chunk [256 dv][64 k]
#pragma unroll
    for (int r = 0; r < 8; ++r) {
      int j = tid + r * 256;
      int dv = j >> 3, k8 = (j & 7) << 3;
      *(uint4*)&hS[dv][k8] = *(const uint4*)(Hb + (size_t)dv * NPOOL + kc * 64 + k8);
    }
    __syncthreads();

    // QK^T: S[16q x 64k] per wave
    f32x4 s[4];
#pragma unroll
    for (int t = 0; t < 4; ++t) s[t] = (f32x4){0.f, 0.f, 0.f, 0.f};
#pragma unroll
    for (int ks = 0; ks < 2; ++ks) {
#pragma unroll
      for (int t = 0; t < 4; ++t) {
        short8 bf = *(const short8*)&fS[t * 16 + col][ks * 32 + rgrp * 8];
        s[t] = __builtin_amdgcn_mfma_f32_16x16x32_bf16(ag[ks], bf, s[t], 0, 0, 0);
      }
    }

    // online softmax; lane owns rows wave*16 + rgrp*4 + r, cols t*16 + col
    float cm[4];
#pragma unroll
    for (int r = 0; r < 4; ++r) {
      cm[r] = fmaxf(fmaxf(s[0][r], s[1][r]), fmaxf(s[2][r], s[3][r]));
#pragma unroll
      for (int msk = 1; msk < 16; msk <<= 1) cm[r] = fmaxf(cm[r], __shfl_xor(cm[r], msk));
    }
    float alpha[4], rs[4];
#pragma unroll
    for (int r = 0; r < 4; ++r) {
      float mn = fmaxf(m_run[r], cm[r]);
      alpha[r] = __expf(m_run[r] - mn);
      m_run[r] = mn;
      rs[r] = 0.f;
    }
    const int prow = wave * 16 + rgrp * 4;
#pragma unroll
    for (int t = 0; t < 4; ++t) {
#pragma unroll
      for (int r = 0; r < 4; ++r) {
        float p = __expf(s[t][r] - m_run[r]);
        rs[r] += p;
        pS[prow + r][t * 16 + col] = __float2bfloat16(p);
      }
    }
#pragma unroll
    for (int r = 0; r < 4; ++r) {
#pragma unroll
      for (int msk = 1; msk < 16; msk <<= 1) rs[r] += __shfl_xor(rs[r], msk);
      l_run[r] = alpha[r] * l_run[r] + rs[r];
    }

    // rescale O
#pragma unroll
    for (int t = 0; t < 16; ++t) {
#pragma unroll
      for (int r = 0; r < 4; ++r) oacc[t][r] *= alpha[r];
    }

    // PV: O[16q x 256dv] += P[16x64] @ h[64x256]
    // (pS rows for this wave were written by this wave only -> no barrier)
    short8 ap[2];
#pragma unroll
    for (int ks = 0; ks < 2; ++ks)
      ap[ks] = *(const short8*)&pS[wave * 16 + col][ks * 32 + rgrp * 8];
#pragma unroll
    for (int t = 0; t < 16; ++t) {
#pragma unroll
      for (int ks = 0; ks < 2; ++ks) {
        short8 bh = *(const short8*)&hS[t * 16 + col][ks * 32 + rgrp * 8];
        oacc[t] = __builtin_amdgcn_mfma_f32_16x16x32_bf16(ap[ks], bh, oacc[t], 0, 0, 0);
      }
    }
  }

  // epilogue: normalize and store fp32
  float inv[4];
#pragma unroll
  for (int r = 0; r < 4; ++r) inv[r] = 1.0f / l_run[r];
  const size_t rowb = (size_t)b * NTOK + qt * 64 + wave * 16 + rgrp * 4;
#pragma unroll
  for (int t = 0; t < 16; ++t) {
#pragma unroll
    for (int r = 0; r < 4; ++r) {
      O[(rowb + r) * 256 + t * 16 + col] = oacc[t][r] * inv[r];
    }
  }
}

extern "C" void kernel_launch(void* const* d_in, const int* in_sizes, int n_in,
                              void* d_out, int out_size, void* d_ws, size_t ws_size,
                              hipStream_t stream) {
  (void)in_sizes; (void)n_in; (void)out_size; (void)ws_size;
  const float* x     = (const float*)d_in[0];  // [8,64,64,512]
  const float* wf    = (const float*)d_in[1];  // [512,64]
  const float* wg    = (const float*)d_in[2];  // [512,64]
  const float* wh    = (const float*)d_in[3];  // [512,256]
  const float* wo    = (const float*)d_in[4];  // [256,512]
  const float* gamma = (const float*)d_in[5];  // [1]
  float* out = (float*)d_out;

  float* oB = (float*)d_ws;                                  // [32768,256] fp32 = 32 MB
  __hip_bfloat16* gB = (__hip_bfloat16*)(oB + 8388608);      // [32768,64] bf16 = 4 MB
  __hip_bfloat16* fB = gB + 2097152;                         // [8192,64]  bf16 = 1 MB
  __hip_bfloat16* hT = fB + 524288;                          // [8,256,1024] bf16 = 4 MB

  dim3 blk(256);
  gemm_fg<false><<<dim3(512, 1), blk, 0, stream>>>(x, wg, gB, 512, 64);
  gemm_fg<true><<<dim3(512, 1), blk, 0, stream>>>(x, wf, fB, 512, 64);
  gemm_hT<<<dim3(512, 4), blk, 0, stream>>>(x, wh, hT, 512, 256);
  attn_mfma<<<512, blk, 0, stream>>>(gB, fB, hT, oB);
  gemm_out<<<dim3(512, 8), blk, 0, stream>>>(oB, wo, out, x, gamma, 256, 512);
}

// Round 4
// 262.007 us; speedup vs baseline: 2.7908x; 1.8167x over previous
//
#include <hip/hip_runtime.h>
#include <hip/hip_bf16.h>

#define NTOK 4096   // 64*64 tokens per batch
#define NPOOL 1024  // 32*32 pooled tokens per batch

using short8 = __attribute__((ext_vector_type(8))) short;
using f32x4  = __attribute__((ext_vector_type(4))) float;

__device__ __forceinline__ unsigned short f2bf(float f) {
  __hip_bfloat16 h = __float2bfloat16(f);
  return __builtin_bit_cast(unsigned short, h);
}

// Map local tile row m (0..63) to a global x row such that rows 4*p..4*p+3 are
// the 2x2 pooling corners of pooled row bx*16+p.
__device__ __forceinline__ int pool_row(int bx, int m) {
  int pg = bx * 16 + (m >> 2);
  int corner = m & 3;
  int batch = pg >> 10;
  int pl = pg & 1023;
  int pi = pl >> 5, pj = pl & 31;
  return (batch << 12) + ((2 * pi + (corner >> 1)) << 6) + 2 * pj + (corner & 1);
}

// Pack weights: wcatT[384][512] = [f(64) | g(64) | h(256)]^T bf16; woT[512][256] bf16.
__global__ __launch_bounds__(256) void pack_w(const float* __restrict__ wf,
                                              const float* __restrict__ wg,
                                              const float* __restrict__ wh,
                                              const float* __restrict__ wo,
                                              unsigned short* __restrict__ wcatT,
                                              unsigned short* __restrict__ woT) {
  int i = blockIdx.x * 256 + threadIdx.x;
  if (i < 384 * 512) {
    int n = i >> 9, k = i & 511;
    float v = (n < 64) ? wf[k * 64 + n]
            : (n < 128) ? wg[k * 64 + (n - 64)]
                        : wh[k * 256 + (n - 128)];
    wcatT[i] = f2bf(v);
  } else if (i < 384 * 512 + 512 * 256) {
    int j = i - 384 * 512;
    int n = j >> 8, k = j & 255;
    woT[j] = f2bf(wo[(size_t)k * 512 + n]);
  }
}

// Fused f/g/h projection, MFMA. Block = 64 x-rows (pool_row-permuted) x 384 cols.
// Outputs: fB[8192][64] bf16 (pooled), gB[32768][64] bf16, hT[8][256][1024] bf16 (pooled,T).
__global__ __launch_bounds__(256) void fgh_proj(const float* __restrict__ x,
                                                const unsigned short* __restrict__ wcatT,
                                                unsigned short* __restrict__ fB,
                                                unsigned short* __restrict__ gB,
                                                unsigned short* __restrict__ hT) {
  __shared__ unsigned short lds[17920];  // As[64][40] @0 ; WsT[384][40] @2560
  const int tid = threadIdx.x;
  const int bx = blockIdx.x;
  const int wave = tid >> 6, lane = tid & 63;
  const int col = lane & 15, rgrp = lane >> 4;

  f32x4 acc[4][6];
#pragma unroll
  for (int mt = 0; mt < 4; ++mt)
#pragma unroll
    for (int nt = 0; nt < 6; ++nt) acc[mt][nt] = (f32x4){0.f, 0.f, 0.f, 0.f};

  for (int kt = 0; kt < 16; ++kt) {
    __syncthreads();
#pragma unroll
    for (int r = 0; r < 2; ++r) {  // x: 64 rows x 32 k, cvt to bf16
      int idx = tid + r * 256;
      int m = idx >> 3, k4 = (idx & 7) << 2;
      float4 v = *(const float4*)(x + (size_t)pool_row(bx, m) * 512 + kt * 32 + k4);
      ushort4 o4;
      o4.x = f2bf(v.x); o4.y = f2bf(v.y); o4.z = f2bf(v.z); o4.w = f2bf(v.w);
      *(ushort4*)&lds[m * 40 + k4] = o4;
    }
#pragma unroll
    for (int r = 0; r < 6; ++r) {  // wcatT: 384 n x 32 k
      int idx = tid + r * 256;
      int n = idx >> 2, k8 = (idx & 3) << 3;
      *(uint4*)&lds[2560 + n * 40 + k8] =
          *(const uint4*)(wcatT + (size_t)n * 512 + kt * 32 + k8);
    }
    __syncthreads();

    short8 am[4];
#pragma unroll
    for (int mt = 0; mt < 4; ++mt)
      am[mt] = *(const short8*)&lds[(mt * 16 + col) * 40 + rgrp * 8];
#pragma unroll
    for (int nt = 0; nt < 6; ++nt) {
      short8 bn = *(const short8*)&lds[2560 + (wave * 96 + nt * 16 + col) * 40 + rgrp * 8];
#pragma unroll
      for (int mt = 0; mt < 4; ++mt)
        acc[mt][nt] = __builtin_amdgcn_mfma_f32_16x16x32_bf16(am[mt], bn, acc[mt][nt], 0, 0, 0);
    }
  }
  __syncthreads();

  // epilogue assembly in LDS (alias over staging)
  unsigned short* gO = lds;          // [64][72]
  unsigned short* fO = lds + 4608;   // [16][72]
  unsigned short* hO = lds + 5760;   // [256][24]
#pragma unroll
  for (int mt = 0; mt < 4; ++mt) {
#pragma unroll
    for (int nt = 0; nt < 6; ++nt) {
      int n = wave * 96 + nt * 16 + col;
      f32x4 a = acc[mt][nt];
      if (n < 64) {
        float mx = fmaxf(fmaxf(a[0], a[1]), fmaxf(a[2], a[3]));
        fO[(mt * 4 + rgrp) * 72 + n] = f2bf(mx);
      } else if (n < 128) {
#pragma unroll
        for (int reg = 0; reg < 4; ++reg)
          gO[(mt * 16 + rgrp * 4 + reg) * 72 + (n - 64)] = f2bf(a[reg]);
      } else {
        float mx = fmaxf(fmaxf(a[0], a[1]), fmaxf(a[2], a[3]));
        hO[(n - 128) * 24 + (mt * 4 + rgrp)] = f2bf(mx);
      }
    }
  }
  __syncthreads();

  const int b = bx >> 6, pkb = (bx & 63) * 16;
#pragma unroll
  for (int r = 0; r < 2; ++r) {  // g: 64 rows x 64 ch (rows permuted)
    int idx = tid + r * 256;
    int m = idx >> 3, d8 = (idx & 7) << 3;
    *(uint4*)(gB + (size_t)pool_row(bx, m) * 64 + d8) = *(const uint4*)&gO[m * 72 + d8];
  }
  if (tid < 128) {               // f: 16 pooled rows x 64 ch
    int pr = tid >> 3, d8 = (tid & 7) << 3;
    *(uint4*)(fB + (size_t)(bx * 16 + pr) * 64 + d8) = *(const uint4*)&fO[pr * 72 + d8];
  }
#pragma unroll
  for (int r = 0; r < 2; ++r) {  // hT: 256 dv x 16 pooled
    int idx = tid + r * 256;
    int dv = idx >> 1, p8 = (idx & 1) << 3;
    *(uint4*)(hT + (((size_t)b * 256 + dv) << 10) + pkb + p8) = *(const uint4*)&hO[dv * 24 + p8];
  }
}

// MFMA flash attention; bf16 output o[32768][256].
__global__ __launch_bounds__(256) void attn_mfma(const __hip_bfloat16* __restrict__ G,
                                                 const __hip_bfloat16* __restrict__ F,
                                                 const __hip_bfloat16* __restrict__ HT,
                                                 unsigned short* __restrict__ O) {
  __shared__ __hip_bfloat16 gS[64][72];   // [q][d]
  __shared__ __hip_bfloat16 fS[64][72];   // [k][d]
  __shared__ __hip_bfloat16 hS[256][72];  // [dv][k]
  __shared__ __hip_bfloat16 pS[64][72];   // [q][k]

  const int tid = threadIdx.x;
  const int wave = tid >> 6, lane = tid & 63;
  const int col = lane & 15;
  const int rgrp = lane >> 4;
  const int b = blockIdx.x >> 6, qt = blockIdx.x & 63;

  const __hip_bfloat16* Gb = G + ((size_t)b * NTOK + qt * 64) * 64;
  const __hip_bfloat16* Fb = F + (size_t)b * NPOOL * 64;
  const __hip_bfloat16* Hb = HT + (size_t)b * 256 * NPOOL;

#pragma unroll
  for (int r = 0; r < 2; ++r) {
    int j = tid + r * 256;
    int q = j >> 3, d8 = (j & 7) << 3;
    *(uint4*)&gS[q][d8] = *(const uint4*)(Gb + (size_t)q * 64 + d8);
  }
  __syncthreads();

  short8 ag[2];
#pragma unroll
  for (int ks = 0; ks < 2; ++ks)
    ag[ks] = *(const short8*)&gS[wave * 16 + col][ks * 32 + rgrp * 8];

  f32x4 oacc[16];
#pragma unroll
  for (int t = 0; t < 16; ++t) oacc[t] = (f32x4){0.f, 0.f, 0.f, 0.f};
  float m_run[4], l_run[4];
#pragma unroll
  for (int r = 0; r < 4; ++r) { m_run[r] = -1e30f; l_run[r] = 0.f; }

  for (int kc = 0; kc < 16; ++kc) {
    __syncthreads();
#pragma unroll
    for (int r = 0; r < 2; ++r) {
      int j = tid + r * 256;
      int k = j >> 3, d8 = (j & 7) << 3;
      *(uint4*)&fS[k][d8] = *(const uint4*)(Fb + (size_t)(kc * 64 + k) * 64 + d8);
    }
#pragma unroll
    for (int r = 0; r < 8; ++r) {
      int j = tid + r * 256;
      int dv = j >> 3, k8 = (j & 7) << 3;
      *(uint4*)&hS[dv][k8] = *(const uint4*)(Hb + (size_t)dv * NPOOL + kc * 64 + k8);
    }
    __syncthreads();

    f32x4 s[4];
#pragma unroll
    for (int t = 0; t < 4; ++t) s[t] = (f32x4){0.f, 0.f, 0.f, 0.f};
#pragma unroll
    for (int ks = 0; ks < 2; ++ks) {
#pragma unroll
      for (int t = 0; t < 4; ++t) {
        short8 bf = *(const short8*)&fS[t * 16 + col][ks * 32 + rgrp * 8];
        s[t] = __builtin_amdgcn_mfma_f32_16x16x32_bf16(ag[ks], bf, s[t], 0, 0, 0);
      }
    }

    float cm[4];
#pragma unroll
    for (int r = 0; r < 4; ++r) {
      cm[r] = fmaxf(fmaxf(s[0][r], s[1][r]), fmaxf(s[2][r], s[3][r]));
#pragma unroll
      for (int msk = 1; msk < 16; msk <<= 1) cm[r] = fmaxf(cm[r], __shfl_xor(cm[r], msk));
    }
    float alpha[4], rs[4];
#pragma unroll
    for (int r = 0; r < 4; ++r) {
      float mn = fmaxf(m_run[r], cm[r]);
      alpha[r] = __expf(m_run[r] - mn);
      m_run[r] = mn;
      rs[r] = 0.f;
    }
    const int prow = wave * 16 + rgrp * 4;
#pragma unroll
    for (int t = 0; t < 4; ++t) {
#pragma unroll
      for (int r = 0; r < 4; ++r) {
        float p = __expf(s[t][r] - m_run[r]);
        rs[r] += p;
        pS[prow + r][t * 16 + col] = __float2bfloat16(p);
      }
    }
#pragma unroll
    for (int r = 0; r < 4; ++r) {
#pragma unroll
      for (int msk = 1; msk < 16; msk <<= 1) rs[r] += __shfl_xor(rs[r], msk);
      l_run[r] = alpha[r] * l_run[r] + rs[r];
    }

#pragma unroll
    for (int t = 0; t < 16; ++t) {
#pragma unroll
      for (int r = 0; r < 4; ++r) oacc[t][r] *= alpha[r];
    }

    short8 ap[2];
#pragma unroll
    for (int ks = 0; ks < 2; ++ks)
      ap[ks] = *(const short8*)&pS[wave * 16 + col][ks * 32 + rgrp * 8];
#pragma unroll
    for (int t = 0; t < 16; ++t) {
#pragma unroll
      for (int ks = 0; ks < 2; ++ks) {
        short8 bh = *(const short8*)&hS[t * 16 + col][ks * 32 + rgrp * 8];
        oacc[t] = __builtin_amdgcn_mfma_f32_16x16x32_bf16(ap[ks], bh, oacc[t], 0, 0, 0);
      }
    }
  }

  // epilogue: normalize, assemble bf16 in LDS (alias hS), coalesced store
  float inv[4];
#pragma unroll
  for (int r = 0; r < 4; ++r) inv[r] = 1.0f / l_run[r];
  __syncthreads();
  unsigned short* oS = (unsigned short*)&hS[0][0];  // [64][264]
  const int qrow = wave * 16 + rgrp * 4;
#pragma unroll
  for (int t = 0; t < 16; ++t) {
#pragma unroll
    for (int r = 0; r < 4; ++r)
      oS[(qrow + r) * 264 + t * 16 + col] = f2bf(oacc[t][r] * inv[r]);
  }
  __syncthreads();
  unsigned short* Ob = O + ((size_t)b * NTOK + qt * 64) * 256;
#pragma unroll
  for (int r = 0; r < 8; ++r) {
    int idx = tid + r * 256;
    int q = idx >> 5, d8 = (idx & 31) << 3;
    *(uint4*)(Ob + (size_t)q * 256 + d8) = *(const uint4*)&oS[q * 264 + d8];
  }
}

// MFMA out-GEMM: out = gamma*(o @ wo) + x. A=o bf16 [32768][256], B=woT[512][256] bf16.
__global__ __launch_bounds__(256) void gemm_out_mfma(const unsigned short* __restrict__ Obf,
                                                     const unsigned short* __restrict__ woT,
                                                     const float* __restrict__ Xres,
                                                     const float* __restrict__ gamma,
                                                     float* __restrict__ Out) {
  __shared__ unsigned short lds[23040];  // As[64][40] @0 ; WsT[512][40] @2560
  const int tid = threadIdx.x;
  const int bx = blockIdx.x;
  const int wave = tid >> 6, lane = tid & 63;
  const int col = lane & 15, rgrp = lane >> 4;

  f32x4 acc[4][8];
#pragma unroll
  for (int mt = 0; mt < 4; ++mt)
#pragma unroll
    for (int nt = 0; nt < 8; ++nt) acc[mt][nt] = (f32x4){0.f, 0.f, 0.f, 0.f};

  for (int kt = 0; kt < 8; ++kt) {
    __syncthreads();
    {  // A: 64 rows x 32 k
      int m = tid >> 2, k8 = (tid & 3) << 3;
      *(uint4*)&lds[m * 40 + k8] =
          *(const uint4*)(Obf + ((size_t)bx * 64 + m) * 256 + kt * 32 + k8);
    }
#pragma unroll
    for (int r = 0; r < 8; ++r) {  // B: 512 n x 32 k
      int idx = tid + r * 256;
      int n = idx >> 2, k8 = (idx & 3) << 3;
      *(uint4*)&lds[2560 + n * 40 + k8] =
          *(const uint4*)(woT + (size_t)n * 256 + kt * 32 + k8);
    }
    __syncthreads();

    short8 am[4];
#pragma unroll
    for (int mt = 0; mt < 4; ++mt)
      am[mt] = *(const short8*)&lds[(mt * 16 + col) * 40 + rgrp * 8];
#pragma unroll
    for (int nt = 0; nt < 8; ++nt) {
      short8 bn = *(const short8*)&lds[2560 + (wave * 128 + nt * 16 + col) * 40 + rgrp * 8];
#pragma unroll
      for (int mt = 0; mt < 4; ++mt)
        acc[mt][nt] = __builtin_amdgcn_mfma_f32_16x16x32_bf16(am[mt], bn, acc[mt][nt], 0, 0, 0);
    }
  }

  float gm = gamma[0];
#pragma unroll
  for (int mt = 0; mt < 4; ++mt) {
#pragma unroll
    for (int nt = 0; nt < 8; ++nt) {
      int n = wave * 128 + nt * 16 + col;
#pragma unroll
      for (int reg = 0; reg < 4; ++reg) {
        size_t row = (size_t)bx * 64 + mt * 16 + rgrp * 4 + reg;
        size_t off = row * 512 + n;
        Out[off] = gm * acc[mt][nt][reg] + Xres[off];
      }
    }
  }
}

extern "C" void kernel_launch(void* const* d_in, const int* in_sizes, int n_in,
                              void* d_out, int out_size, void* d_ws, size_t ws_size,
                              hipStream_t stream) {
  (void)in_sizes; (void)n_in; (void)out_size; (void)ws_size;
  const float* x     = (const float*)d_in[0];
  const float* wf    = (const float*)d_in[1];
  const float* wg    = (const float*)d_in[2];
  const float* wh    = (const float*)d_in[3];
  const float* wo    = (const float*)d_in[4];
  const float* gamma = (const float*)d_in[5];
  float* out = (float*)d_out;

  unsigned short* ws = (unsigned short*)d_ws;
  unsigned short* oB    = ws;               // [32768][256] bf16
  unsigned short* gB    = ws + 8388608;     // [32768][64]
  unsigned short* fB    = ws + 10485760;    // [8192][64]
  unsigned short* hT    = ws + 11010048;    // [8][256][1024]
  unsigned short* wcatT = ws + 13107200;    // [384][512]
  unsigned short* woT   = ws + 13303808;    // [512][256]

  dim3 blk(256);
  pack_w<<<1280, blk, 0, stream>>>(wf, wg, wh, wo, wcatT, woT);
  fgh_proj<<<512, blk, 0, stream>>>(x, wcatT, fB, gB, hT);
  attn_mfma<<<512, blk, 0, stream>>>((const __hip_bfloat16*)gB, (const __hip_bfloat16*)fB,
                                     (const __hip_bfloat16*)hT, oB);
  gemm_out_mfma<<<512, blk, 0, stream>>>(oB, woT, x, gamma, out);
}